// Round 7
// baseline (625.125 us; speedup 1.0000x reference)
//
#include <hip/hip_runtime.h>
#include <hip/hip_bf16.h>
#include <stdint.h>

#define AS1 __attribute__((address_space(1)))
#define AS3 __attribute__((address_space(3)))

typedef __attribute__((ext_vector_type(8))) __bf16 bf16x8;
typedef __attribute__((ext_vector_type(4))) float f32x4;
typedef unsigned short u16;
typedef __attribute__((ext_vector_type(8))) unsigned short u16x8;

// ---- problem sizes (fixed for this module) ----
#define B_    8
#define S_    512
#define NH_   12
#define HD_   768
#define NHD_  (NH_*HD_)     // 9216
#define D3_   (3*NHD_)      // 27648
#define QK_SCALE 0.03608439182435161f   // 1/sqrt(768)

__device__ __forceinline__ u16 f2bf(float x) {
  union { float f; unsigned u; } a; a.f = x;
  unsigned r = a.u + 0x7fffu + ((a.u >> 16) & 1u);   // RNE
  return (u16)(r >> 16);
}
__device__ __forceinline__ float bf2f(u16 x) {
  union { unsigned u; float f; } a; a.u = ((unsigned)x) << 16; return a.f;
}

__device__ __forceinline__ void gload16(const void* g, void* l) {
  // async global->LDS; LDS dest = wave-uniform base + lane*16, global src per-lane
  __builtin_amdgcn_global_load_lds((const AS1 void*)g, (AS3 void*)l, 16, 0, 0);
}

__device__ __forceinline__ void wg_bar() {
  asm volatile("" ::: "memory");
  __builtin_amdgcn_s_barrier();
  asm volatile("" ::: "memory");
}

// ============================================================================
// 256x256 GEMM, BK=64, 8 waves (2M x 4N; per-wave C = 128x64), m201 8-phase.
// LDS 128KB: A[2][256][64], B[2][256][64] bf16, rows 128B.
// Swizzle (verified r6: 0 conflicts): logical col16 c of row r at phys c^(r&7);
//   staging pre-swizzles global source col: slot tid&7 <- col16 (tid&7)^((tid>>3)&7);
//   read: phys col16 = (kk*4 + (lane>>4)) ^ (lane&7)  [row&7 == lane&7].
// Phases per K-tile pair (buf0 = even K-tile, buf1 = odd):
//  ph1 reads A(mi0-3)+B(ni0-1), ph2 reads B(ni2-3), ph3 reads A(mi4-7)+stageB,
//  ph4 stageA + vmcnt, each: {reads|stage -> bar -> 16 MFMA -> bar}; ph5-8 same on buf1.
// vmcnt ledger (4 gloads per stage call, A+B = 8/K-tile): at ph4/ph8 outstanding
//  = K(t+1):8 + K(t+2):8 -> vmcnt(8) drains exactly K(t+1) before its first read.
//  Last iteration: vmcnt(0) at ph4, none at ph8.
// WAR: stageB at ph3 overwrites B-slot last read ph2 (past ph2 closing bar);
//  stageA at ph4 overwrites A-slot last read ph3. Same for ph7/ph8 on buf1.
// MODE 0: QKV -> scatter Q,K (z,s,h), Vt (z,h,s) bf16, +bias  (SWZ 1-D grid)
// MODE 1: scores -> S bf16 [z][row][col] * QK_SCALE
// MODE 2: AV     -> H bf16 at (bb*512+row)*9216 + n*768 + col
// MODE 3: out-proj split-K partial -> fp32 Part[z][row][col]
// ============================================================================
struct GP2 {
  const u16 *A, *B;     // row-major, C = A * B^T
  int lda, ldb;
  long sA, sB;          // per-z element offsets
  void *o0, *o1, *o2;
  const float* bias;
  int mtMask, mtShift;  // SWZ mode only
};

#define LOADA(DST, BUF, MIB)                                                   \
  _Pragma("unroll") for (int mi = 0; mi < 4; ++mi) {                           \
    DST[mi][0] = *(const bf16x8*)((BUF) + rowA + (MIB + mi) * 2048 + cs0);     \
    DST[mi][1] = *(const bf16x8*)((BUF) + rowA + (MIB + mi) * 2048 + cs1);     \
  }
#define LOADB(DST, BUF, NIB)                                                   \
  _Pragma("unroll") for (int ni = 0; ni < 2; ++ni) {                           \
    DST[ni][0] = *(const bf16x8*)((BUF) + rowB + (NIB + ni) * 2048 + cs0);     \
    DST[ni][1] = *(const bf16x8*)((BUF) + rowB + (NIB + ni) * 2048 + cs1);     \
  }
#define MFMAQ(MI0, NI0, AV, BV)                                                \
  __builtin_amdgcn_s_setprio(1);                                               \
  _Pragma("unroll") for (int mi = 0; mi < 4; ++mi)                             \
    _Pragma("unroll") for (int ni = 0; ni < 2; ++ni)                           \
      _Pragma("unroll") for (int kk = 0; kk < 2; ++kk)                         \
        acc[MI0 + mi][NI0 + ni] = __builtin_amdgcn_mfma_f32_16x16x32_bf16(     \
            AV[mi][kk], BV[ni][kk], acc[MI0 + mi][NI0 + ni], 0, 0, 0);         \
  __builtin_amdgcn_s_setprio(0);

template<int NKT, int MODE, int SWZ>
__global__ __launch_bounds__(512, 2)
void gemm256(GP2 p) {
  __shared__ __align__(16) char smem[131072];
  char* ldsA0 = smem;
  char* ldsA1 = smem + 32768;
  char* ldsB0 = smem + 65536;
  char* ldsB1 = smem + 98304;
  const int tid = threadIdx.x, wid = tid >> 6, lane = tid & 63;
  const int wm = wid >> 2, wn = wid & 3;

  int m_idx, n_idx, z;
  if constexpr (SWZ) {
    const int cpx = (int)gridDim.x >> 3;
    const int bid = (int)blockIdx.x;
    const int tile = (bid & 7) * cpx + (bid >> 3);   // bijective: nwg % 8 == 0
    m_idx = tile & p.mtMask; n_idx = tile >> p.mtShift; z = 0;
  } else {
    m_idx = blockIdx.y; n_idx = blockIdx.x; z = blockIdx.z;
  }
  const long bm0 = (long)m_idx * 256, bn0 = (long)n_idx * 256;

  // staging addresses (pre-swizzled source column)
  const int scol = ((tid & 7) ^ ((tid >> 3) & 7)) * 8;   // elements
  const u16* gA = p.A + (long)z * p.sA + (bm0 + (tid >> 3)) * (long)p.lda + scol;
  const u16* gB = p.B + (long)z * p.sB + (bn0 + (tid >> 3)) * (long)p.ldb + scol;
  const int dW = wid * 1024;   // wave-uniform LDS chunk offset

  auto stageA = [&](int kt) {   // 4 gloads, 256 rows x 64 cols
    char* d = ((kt & 1) ? ldsA1 : ldsA0) + dW;
    const u16* s = gA + kt * 64;
    gload16(s,                      d);
    gload16(s + (size_t) 64 * p.lda, d + 8192);
    gload16(s + (size_t)128 * p.lda, d + 16384);
    gload16(s + (size_t)192 * p.lda, d + 24576);
  };
  auto stageB = [&](int kt) {
    char* d = ((kt & 1) ? ldsB1 : ldsB0) + dW;
    const u16* s = gB + kt * 64;
    gload16(s,                      d);
    gload16(s + (size_t) 64 * p.ldb, d + 8192);
    gload16(s + (size_t)128 * p.ldb, d + 16384);
    gload16(s + (size_t)192 * p.ldb, d + 24576);
  };

  f32x4 acc[8][4];
  const f32x4 zero4 = {0.f, 0.f, 0.f, 0.f};
#pragma unroll
  for (int i = 0; i < 8; ++i)
#pragma unroll
    for (int j = 0; j < 4; ++j) acc[i][j] = zero4;

  // fragment read offsets
  const int rowA = (wm * 128 + (lane & 15)) * 128;
  const int rowB = (wn * 64  + (lane & 15)) * 128;
  const int cs0 = (((lane >> 4)    ) ^ (lane & 7)) << 4;
  const int cs1 = ((4 + (lane >> 4)) ^ (lane & 7)) << 4;

  // prologue: K0 (8 gloads) then K1 (8); drain K0, keep K1 in flight
  stageA(0); stageB(0);
  stageB(1); stageA(1);
  asm volatile("s_waitcnt vmcnt(8)" ::: "memory");
  wg_bar();

  bf16x8 aF[4][2], b01[2][2], b23[2][2];

  for (int i = 0; i < NKT / 2; ++i) {
    const bool st = (i + 1 < NKT / 2);
    const int kt2 = 2 * i + 2, kt3 = 2 * i + 3;

    // ===== K-tile 2i (buf0) =====
    LOADA(aF, ldsA0, 0); LOADB(b01, ldsB0, 0);            // ph1
    wg_bar(); MFMAQ(0, 0, aF, b01); wg_bar();
    LOADB(b23, ldsB0, 2);                                 // ph2
    wg_bar(); MFMAQ(0, 2, aF, b23); wg_bar();
    LOADA(aF, ldsA0, 4);                                  // ph3
    if (st) stageB(kt2);
    wg_bar(); MFMAQ(4, 0, aF, b01); wg_bar();
    if (st) stageA(kt2);                                  // ph4
    wg_bar(); MFMAQ(4, 2, aF, b23);
    if (st) { asm volatile("s_waitcnt vmcnt(8)" ::: "memory"); }
    else    { asm volatile("s_waitcnt vmcnt(0)" ::: "memory"); }
    wg_bar();

    // ===== K-tile 2i+1 (buf1) =====
    LOADA(aF, ldsA1, 0); LOADB(b01, ldsB1, 0);            // ph5
    wg_bar(); MFMAQ(0, 0, aF, b01); wg_bar();
    LOADB(b23, ldsB1, 2);                                 // ph6
    wg_bar(); MFMAQ(0, 2, aF, b23); wg_bar();
    LOADA(aF, ldsA1, 4);                                  // ph7
    if (st) stageB(kt3);
    wg_bar(); MFMAQ(4, 0, aF, b01); wg_bar();
    if (st) stageA(kt3);                                  // ph8
    wg_bar(); MFMAQ(4, 2, aF, b23);
    if (st) { asm volatile("s_waitcnt vmcnt(8)" ::: "memory"); }
    wg_bar();
  }

  // epilogue: C/D layout col = lane&15, row = (lane>>4)*4 + reg  [m89]
  const int r0 = (int)bm0 + wm * 128 + ((lane >> 4) << 2);
  const int c0 = (int)bn0 + wn * 64 + (lane & 15);
#pragma unroll
  for (int mi = 0; mi < 8; ++mi) {
#pragma unroll
    for (int ni = 0; ni < 4; ++ni) {
      const int col = c0 + ni * 16;
      if constexpr (MODE == 0) {
        const int which = col / NHD_;
        const int rem = col - which * NHD_;
        const int n = rem / HD_;
        const int h = rem - n * HD_;
        const float bs = p.bias[col];
#pragma unroll
        for (int r = 0; r < 4; ++r) {
          const int row = r0 + mi * 16 + r;
          const float v = acc[mi][ni][r] + bs;
          const int bb = row >> 9, s = row & 511;
          const long zz = (long)(bb * NH_ + n);
          if (which == 0)      ((u16*)p.o0)[zz * (long)(S_*HD_) + (long)s * HD_ + h] = f2bf(v);
          else if (which == 1) ((u16*)p.o1)[zz * (long)(S_*HD_) + (long)s * HD_ + h] = f2bf(v);
          else                 ((u16*)p.o2)[zz * (long)(S_*HD_) + (long)h * S_  + s] = f2bf(v);
        }
      } else if constexpr (MODE == 1) {
#pragma unroll
        for (int r = 0; r < 4; ++r) {
          const int row = r0 + mi * 16 + r;
          ((u16*)p.o0)[(long)z * S_ * S_ + (long)row * S_ + col] = f2bf(acc[mi][ni][r] * QK_SCALE);
        }
      } else if constexpr (MODE == 2) {
        const int bb = z / NH_, n = z - bb * NH_;
#pragma unroll
        for (int r = 0; r < 4; ++r) {
          const int row = r0 + mi * 16 + r;
          ((u16*)p.o0)[(long)(bb * S_ + row) * NHD_ + n * HD_ + col] = f2bf(acc[mi][ni][r]);
        }
      } else {
        const long rowsTot = (long)gridDim.y * 256;
#pragma unroll
        for (int r = 0; r < 4; ++r) {
          const int row = r0 + mi * 16 + r;
          ((float*)p.o0)[((long)z * rowsTot + row) * HD_ + col] = acc[mi][ni][r];
        }
      }
    }
  }
}

// one wave per row (512 cols, bf16 in/out): +mask, softmax
__global__ __launch_bounds__(256)
void softmax_rows(const u16* __restrict__ S, u16* __restrict__ P,
                  const float* __restrict__ maskc) {
  const int wave = threadIdx.x >> 6, lane = threadIdx.x & 63;
  const int rid = blockIdx.x * 4 + wave;
  const int z = rid >> 9;
  const int b = z / NH_;
  const u16x8 sv = *(const u16x8*)(S + (size_t)rid * S_ + lane*8);
  const float* mrow = maskc + (size_t)b * S_;
  float vals[8];
  float m = -3.4e38f;
#pragma unroll
  for (int j = 0; j < 8; ++j) {
    vals[j] = bf2f(sv[j]) + mrow[lane*8 + j];
    m = fmaxf(m, vals[j]);
  }
#pragma unroll
  for (int o = 32; o > 0; o >>= 1) m = fmaxf(m, __shfl_xor(m, o));
  float sum = 0.f;
#pragma unroll
  for (int j = 0; j < 8; ++j) { vals[j] = __expf(vals[j] - m); sum += vals[j]; }
#pragma unroll
  for (int o = 32; o > 0; o >>= 1) sum += __shfl_xor(sum, o);
  const float inv = 1.0f / sum;
  u16x8 pv;
#pragma unroll
  for (int j = 0; j < 8; ++j) pv[j] = f2bf(vals[j] * inv);
  *(u16x8*)(P + (size_t)rid * S_ + lane*8) = pv;
}

__global__ __launch_bounds__(256)
void cvt_bf16(const float4* __restrict__ in, ushort4* __restrict__ out, int n4) {
  const int i = blockIdx.x * 256 + threadIdx.x;
  if (i >= n4) return;
  const float4 v = in[i];
  ushort4 o;
  o.x = f2bf(v.x); o.y = f2bf(v.y); o.z = f2bf(v.z); o.w = f2bf(v.w);
  out[i] = o;
}

// out = sum of 4 fp32 partials + bias; n4 = rows_c*768/4 (float4 units)
__global__ __launch_bounds__(256)
void combine_out(const float4* __restrict__ part, const float* __restrict__ b,
                 float4* __restrict__ out, int n4) {
  const int i = blockIdx.x * 256 + threadIdx.x;
  if (i >= n4) return;
  const float4 a0 = part[i];
  const float4 a1 = part[i + (size_t)n4];
  const float4 a2 = part[i + (size_t)2*n4];
  const float4 a3 = part[i + (size_t)3*n4];
  const int c = (i * 4) % HD_;
  float4 o;
  o.x = a0.x + a1.x + a2.x + a3.x + b[c];
  o.y = a0.y + a1.y + a2.y + a3.y + b[c+1];
  o.z = a0.z + a1.z + a2.z + a3.z + b[c+2];
  o.w = a0.w + a1.w + a2.w + a3.w + b[c+3];
  out[i] = o;
}

extern "C" void kernel_launch(void* const* d_in, const int* in_sizes, int n_in,
                              void* d_out, int out_size, void* d_ws, size_t ws_size,
                              hipStream_t stream) {
  const float* x     = (const float*)d_in[0];
  const float* mask  = (const float*)d_in[1];
  const float* w_qkv = (const float*)d_in[2];
  const float* b_qkv = (const float*)d_in[3];
  const float* w_o   = (const float*)d_in[4];
  const float* b_o   = (const float*)d_in[5];
  float* out = (float*)d_out;

  // adaptive batch-chunked workspace (layout proven rounds 2-6)
  int bc = 0;
  for (int c = 8; c >= 1; c >>= 1)
    if (56623104UL + (unsigned long)c*35389440UL <= ws_size) { bc = c; break; }
  if (bc == 0) return;

  char* ws = (char*)d_ws;
  u16* wqb = (u16*)(ws);
  u16* wob = (u16*)(ws + 42467328L);
  u16* xb  = (u16*)(ws + 56623104L);
  long off = 56623104L + (long)bc*786432L;
  u16* Q   = (u16*)(ws + off);  off += (long)bc*9437184L;
  u16* Kb  = (u16*)(ws + off);  off += (long)bc*9437184L;
  u16* Vt  = (u16*)(ws + off);  off += (long)bc*9437184L;
  u16* Sb  = (u16*)(ws + off);
  u16* Pb  = Kb;                 // alias
  u16* H   = Q;                  // alias
  float* Part = (float*)Sb;      // alias (4 x rows_c x 768 fp32 = Sb bytes)

  cvt_bf16<<<dim3(D3_*HD_/4/256), dim3(256), 0, stream>>>((const float4*)w_qkv, (ushort4*)wqb, D3_*HD_/4);
  cvt_bf16<<<dim3(HD_*NHD_/4/256), dim3(256), 0, stream>>>((const float4*)w_o, (ushort4*)wob, HD_*NHD_/4);

  const int nchunks = B_ / bc;
  const int rows_c = bc * S_;
  const int zc = bc * NH_;
  const int Mt2 = rows_c / 256;            // {2,4,8,16}
  const int mtShift = __builtin_ctz(Mt2);

  for (int c = 0; c < nchunks; ++c) {
    const long row0 = (long)c * rows_c;

    cvt_bf16<<<dim3(rows_c*HD_/4/256), dim3(256), 0, stream>>>(
        (const float4*)(x + row0*HD_), (ushort4*)xb, rows_c*HD_/4);

    GP2 p1; p1.A = xb; p1.B = wqb; p1.lda = HD_; p1.ldb = HD_;
    p1.sA = 0; p1.sB = 0; p1.o0 = Q; p1.o1 = Kb; p1.o2 = Vt; p1.bias = b_qkv;
    p1.mtMask = Mt2 - 1; p1.mtShift = mtShift;
    gemm256<12, 0, 1><<<dim3((D3_/256) * Mt2), dim3(512), 0, stream>>>(p1);

    GP2 p2; p2.A = Q; p2.B = Kb; p2.lda = HD_; p2.ldb = HD_;
    p2.sA = (long)S_*HD_; p2.sB = (long)S_*HD_;
    p2.o0 = Sb; p2.o1 = nullptr; p2.o2 = nullptr; p2.bias = nullptr;
    p2.mtMask = 0; p2.mtShift = 0;
    gemm256<12, 1, 0><<<dim3(2, 2, zc), dim3(512), 0, stream>>>(p2);

    softmax_rows<<<dim3(zc*S_/4), dim3(256), 0, stream>>>(Sb, Pb, mask + (long)c*bc*S_);

    GP2 p3; p3.A = Pb; p3.B = Vt; p3.lda = S_; p3.ldb = S_;
    p3.sA = (long)S_*S_; p3.sB = (long)S_*HD_;
    p3.o0 = H; p3.o1 = nullptr; p3.o2 = nullptr; p3.bias = nullptr;
    p3.mtMask = 0; p3.mtShift = 0;
    gemm256<8, 2, 0><<<dim3(3, 2, zc), dim3(512), 0, stream>>>(p3);

    // out projection: split-K(4) partials into Sb (dead), then combine + bias
    GP2 p4; p4.A = H; p4.B = wob; p4.lda = NHD_; p4.ldb = NHD_;
    p4.sA = NHD_/4; p4.sB = NHD_/4;   // z indexes the K-chunk (2304 elements)
    p4.o0 = Part; p4.o1 = nullptr; p4.o2 = nullptr; p4.bias = nullptr;
    p4.mtMask = 0; p4.mtShift = 0;
    gemm256<36, 3, 0><<<dim3(3, rows_c/256, 4), dim3(512), 0, stream>>>(p4);

    combine_out<<<dim3(rows_c*HD_/4/256), dim3(256), 0, stream>>>(
        (const float4*)Part, b_o, (float4*)(out + row0*HD_), rows_c*HD_/4);
  }
}

// Round 8
// 613.459 us; speedup vs baseline: 1.0190x; 1.0190x over previous
//
#include <hip/hip_runtime.h>
#include <hip/hip_bf16.h>
#include <stdint.h>

#define AS1 __attribute__((address_space(1)))
#define AS3 __attribute__((address_space(3)))

typedef __attribute__((ext_vector_type(8))) __bf16 bf16x8;
typedef __attribute__((ext_vector_type(4))) float f32x4;
typedef unsigned short u16;
typedef __attribute__((ext_vector_type(8))) unsigned short u16x8;

// ---- problem sizes (fixed for this module) ----
#define B_    8
#define S_    512
#define NH_   12
#define HD_   768
#define NHD_  (NH_*HD_)     // 9216
#define D3_   (3*NHD_)      // 27648
#define QKLD_ (2*NHD_)      // 18432: natural Q|K layout leading dim
#define QK_SCALE 0.03608439182435161f   // 1/sqrt(768)

__device__ __forceinline__ u16 f2bf(float x) {
  union { float f; unsigned u; } a; a.f = x;
  unsigned r = a.u + 0x7fffu + ((a.u >> 16) & 1u);   // RNE
  return (u16)(r >> 16);
}
__device__ __forceinline__ float bf2f(u16 x) {
  union { unsigned u; float f; } a; a.u = ((unsigned)x) << 16; return a.f;
}

__device__ __forceinline__ void gload16(const void* g, void* l) {
  // async global->LDS; LDS dest = wave-uniform base + lane*16, global src per-lane
  __builtin_amdgcn_global_load_lds((const AS1 void*)g, (AS3 void*)l, 16, 0, 0);
}

// ============================================================================
// 128x128 GEMM, 256 threads (2x2 waves), BK=64, single-buffer 32KB LDS,
// 5 blocks/CU (160KB LDS cap) -> cross-block TLP hides prologue/epilogue
// (short-K regime; proven best structure, round 6).
// T2 XOR swizzle (verified 0 conflicts, round 6): logical col16 c of row r at
// phys c^(r&7); staging pre-swizzles global source col; read XORs with lane&7.
// z decomposition: zb = z/12, zn = z%12; operand offset = zb*sXb + zn*sXn.
// MODE 0: QKV proj. Block-uniform third (bn0/9216):
//         which<2 -> natural [row][18432] u16 (contiguous, no scatter);
//         which==2 -> Vt (z,h,s) bf16, PACKED ushort4 stores (s-contiguous).
// MODE 1: scores -> S bf16 [z][row][col] * QK_SCALE
// MODE 2: AV     -> H at (bb*512+row)*18432 + n*768 + col  (Q-section alias)
// MODE 3: out-proj split-K partial -> fp32 Part[z][row][col]
// ============================================================================
struct GP {
  const u16* A;   // + zb*sAb + zn*sAn, row-major lda
  const u16* B;   // + zb*sBb + zn*sBn, row-major ldb  (C = A * B^T)
  int K, lda, ldb;
  long sAb, sAn, sBb, sBn;
  void* o0; void* o2;
  const float* bias;
};

template<int MODE>
__global__ __launch_bounds__(256)
void gemm_bt(GP p) {
  __shared__ __align__(16) char smem[32768];   // A tile 16KB | B tile 16KB
  const int tid  = threadIdx.x;
  const int wave = tid >> 6, lane = tid & 63;
  const int wr = wave >> 1, wc = wave & 1;     // 2x2 waves, 64x64 each
  const int bm0 = blockIdx.y * 128;
  const int bn0 = blockIdx.x * 128;
  const int z   = blockIdx.z;
  const int zb  = z / NH_, zn = z - zb * NH_;

  const u16* A  = p.A + zb * p.sAb + zn * p.sAn;
  const u16* Bm = p.B + zb * p.sBb + zn * p.sBn;

  f32x4 acc[4][4];
  const f32x4 zero4 = {0.f, 0.f, 0.f, 0.f};
#pragma unroll
  for (int i = 0; i < 4; ++i)
#pragma unroll
    for (int j = 0; j < 4; ++j) acc[i][j] = zero4;

  // staging with pre-swizzled source column (verified round 6)
  const int scolsw = ((lane & 7) ^ (lane >> 3)) * 8;   // elements
  const u16* gA = A  + (size_t)(bm0 + wave*8 + (lane>>3)) * p.lda + scolsw;
  const u16* gB = Bm + (size_t)(bn0 + wave*8 + (lane>>3)) * p.ldb + scolsw;
  char* ldsA = smem;
  char* ldsB = smem + 16384;
  char* stA  = ldsA + wave*1024;
  char* stB  = ldsB + wave*1024;

  // fragment read bases (row part) + per-kk swizzled column offsets
  const int aRow = (wr*64 + (lane&15)) * 128;
  const int bRow = (wc*64 + (lane&15)) * 128;
  const int csw  = lane & 7;
  const int cOff0 = (((lane>>4)    ) ^ csw) << 4;   // kk=0
  const int cOff1 = ((4 + (lane>>4)) ^ csw) << 4;   // kk=1

  for (int k0 = 0; k0 < p.K; k0 += 64) {
#pragma unroll
    for (int i = 0; i < 4; ++i) {
      gload16(gA + (size_t)i*32*p.lda, stA + i*4096);
      gload16(gB + (size_t)i*32*p.ldb, stB + i*4096);
    }
    gA += 64; gB += 64;
    __syncthreads();
#pragma unroll
    for (int kk = 0; kk < 2; ++kk) {
      const int cOff = kk ? cOff1 : cOff0;
      bf16x8 av[4], bv[4];
#pragma unroll
      for (int i = 0; i < 4; ++i)
        av[i] = *(const bf16x8*)(ldsA + aRow + i*2048 + cOff);
#pragma unroll
      for (int j = 0; j < 4; ++j)
        bv[j] = *(const bf16x8*)(ldsB + bRow + j*2048 + cOff);
#pragma unroll
      for (int i = 0; i < 4; ++i)
#pragma unroll
        for (int j = 0; j < 4; ++j)
          acc[i][j] = __builtin_amdgcn_mfma_f32_16x16x32_bf16(av[i], bv[j], acc[i][j], 0, 0, 0);
    }
    __syncthreads();
  }

  // epilogue: C/D layout col = lane&15, row = (lane>>4)*4 + reg  [m89]
  const int r0 = bm0 + wr*64 + ((lane>>4) << 2);
  const int c0 = bn0 + wc*64 + (lane&15);

  if constexpr (MODE == 0) {
    if (bn0 < QKLD_) {
      // natural Q|K: contiguous [row][18432], no per-element scatter math
#pragma unroll
      for (int i = 0; i < 4; ++i) {
        u16* rbase = (u16*)p.o0 + (long)(r0 + i*16) * QKLD_;
#pragma unroll
        for (int j = 0; j < 4; ++j) {
          const int col = c0 + j*16;
          const float bs = p.bias[col];
#pragma unroll
          for (int r = 0; r < 4; ++r)
            rbase[(long)r * QKLD_ + col] = f2bf(acc[i][j][r] + bs);
        }
      }
    } else {
      // V third -> Vt (z,h,s), 4 consecutive s per acc quad -> packed store
#pragma unroll
      for (int i = 0; i < 4; ++i) {
        const int rowq = r0 + i*16;
        const int s0 = rowq & 511;
        const int bb = rowq >> 9;
#pragma unroll
        for (int j = 0; j < 4; ++j) {
          const int col = c0 + j*16;
          const int vcol = col - QKLD_;
          const int n = vcol / HD_;
          const int h = vcol - n*HD_;
          const float bs = p.bias[col];
          ushort4 pk;
          pk.x = f2bf(acc[i][j][0] + bs);
          pk.y = f2bf(acc[i][j][1] + bs);
          pk.z = f2bf(acc[i][j][2] + bs);
          pk.w = f2bf(acc[i][j][3] + bs);
          *(ushort4*)((u16*)p.o2 + (long)(bb*NH_ + n)*(S_*HD_) + (long)h*S_ + s0) = pk;
        }
      }
    }
  } else {
#pragma unroll
    for (int i = 0; i < 4; ++i) {
#pragma unroll
      for (int j = 0; j < 4; ++j) {
        const int col = c0 + j*16;
#pragma unroll
        for (int r = 0; r < 4; ++r) {
          const int row = r0 + i*16 + r;
          const float v = acc[i][j][r];
          if constexpr (MODE == 1) {
            ((u16*)p.o0)[(long)z*S_*S_ + (long)row*S_ + col] = f2bf(v * QK_SCALE);
          } else if constexpr (MODE == 2) {
            ((u16*)p.o0)[(long)(zb*S_ + row)*QKLD_ + zn*HD_ + col] = f2bf(v);
          } else {
            ((float*)p.o0)[((long)z * gridDim.y * 128 + row) * HD_ + col] = v;
          }
        }
      }
    }
  }
}

// one wave per row (512 cols, bf16, IN-PLACE): +mask, softmax
__global__ __launch_bounds__(256)
void softmax_rows(u16* __restrict__ SP, const float* __restrict__ maskc) {
  const int wave = threadIdx.x >> 6, lane = threadIdx.x & 63;
  const int rid = blockIdx.x * 4 + wave;
  const int z = rid >> 9;
  const int b = z / NH_;
  const u16x8 sv = *(const u16x8*)(SP + (size_t)rid * S_ + lane*8);
  const float* mrow = maskc + (size_t)b * S_;
  float vals[8];
  float m = -3.4e38f;
#pragma unroll
  for (int j = 0; j < 8; ++j) {
    vals[j] = bf2f(sv[j]) + mrow[lane*8 + j];
    m = fmaxf(m, vals[j]);
  }
#pragma unroll
  for (int o = 32; o > 0; o >>= 1) m = fmaxf(m, __shfl_xor(m, o));
  float sum = 0.f;
#pragma unroll
  for (int j = 0; j < 8; ++j) { vals[j] = __expf(vals[j] - m); sum += vals[j]; }
#pragma unroll
  for (int o = 32; o > 0; o >>= 1) sum += __shfl_xor(sum, o);
  const float inv = 1.0f / sum;
  u16x8 pv;
#pragma unroll
  for (int j = 0; j < 8; ++j) pv[j] = f2bf(vals[j] * inv);
  *(u16x8*)(SP + (size_t)rid * S_ + lane*8) = pv;
}

__global__ __launch_bounds__(256)
void cvt_bf16(const float4* __restrict__ in, ushort4* __restrict__ out, int n4) {
  const int i = blockIdx.x * 256 + threadIdx.x;
  if (i >= n4) return;
  const float4 v = in[i];
  ushort4 o;
  o.x = f2bf(v.x); o.y = f2bf(v.y); o.z = f2bf(v.z); o.w = f2bf(v.w);
  out[i] = o;
}

// out = sum of 4 fp32 partials + bias; n4 = rows_c*768/4 (float4 units)
__global__ __launch_bounds__(256)
void combine_out(const float4* __restrict__ part, const float* __restrict__ b,
                 float4* __restrict__ out, int n4) {
  const int i = blockIdx.x * 256 + threadIdx.x;
  if (i >= n4) return;
  const float4 a0 = part[i];
  const float4 a1 = part[i + (size_t)n4];
  const float4 a2 = part[i + (size_t)2*n4];
  const float4 a3 = part[i + (size_t)3*n4];
  const int c = (i * 4) % HD_;
  float4 o;
  o.x = a0.x + a1.x + a2.x + a3.x + b[c];
  o.y = a0.y + a1.y + a2.y + a3.y + b[c+1];
  o.z = a0.z + a1.z + a2.z + a3.z + b[c+2];
  o.w = a0.w + a1.w + a2.w + a3.w + b[c+3];
  out[i] = o;
}

extern "C" void kernel_launch(void* const* d_in, const int* in_sizes, int n_in,
                              void* d_out, int out_size, void* d_ws, size_t ws_size,
                              hipStream_t stream) {
  const float* x     = (const float*)d_in[0];
  const float* mask  = (const float*)d_in[1];
  const float* w_qkv = (const float*)d_in[2];
  const float* b_qkv = (const float*)d_in[3];
  const float* w_o   = (const float*)d_in[4];
  const float* b_o   = (const float*)d_in[5];
  float* out = (float*)d_out;

  // workspace (same footprint as rounds 2-7 -> bc=8 preserved):
  // fixed: wqb 42,467,328 | wob 14,155,776  (= 56,623,104)
  // per-bc: xb 786,432 | QKVnat (natural Q|K) 18,874,368 | Vt 9,437,184 |
  //         SP 6,291,456   (= 35,389,440 per bc)
  // aliases: P = SP in-place; H = QKVnat Q-section (ld 18432, dead after
  //          scores); Part = SP (P dead after AV)
  int bc = 0;
  for (int c = 8; c >= 1; c >>= 1)
    if (56623104UL + (unsigned long)c*35389440UL <= ws_size) { bc = c; break; }
  if (bc == 0) return;

  char* ws = (char*)d_ws;
  u16* wqb = (u16*)(ws);
  u16* wob = (u16*)(ws + 42467328L);
  u16* xb  = (u16*)(ws + 56623104L);
  long off = 56623104L + (long)bc*786432L;
  u16* QKn = (u16*)(ws + off);  off += (long)bc*18874368L;
  u16* Vt  = (u16*)(ws + off);  off += (long)bc*9437184L;
  u16* SP  = (u16*)(ws + off);
  u16* H   = QKn;                // alias: Q-section, ld 18432
  float* Part = (float*)SP;      // alias: 4 x rows_c x 768 fp32 = SP bytes

  cvt_bf16<<<dim3(D3_*HD_/4/256), dim3(256), 0, stream>>>((const float4*)w_qkv, (ushort4*)wqb, D3_*HD_/4);
  cvt_bf16<<<dim3(HD_*NHD_/4/256), dim3(256), 0, stream>>>((const float4*)w_o, (ushort4*)wob, HD_*NHD_/4);

  const int nchunks = B_ / bc;
  const int rows_c = bc * S_;
  const int zc = bc * NH_;

  for (int c = 0; c < nchunks; ++c) {
    const long row0 = (long)c * rows_c;

    cvt_bf16<<<dim3(rows_c*HD_/4/256), dim3(256), 0, stream>>>(
        (const float4*)(x + row0*HD_), (ushort4*)xb, rows_c*HD_/4);

    // QKV: A = xb [rows_c][768], B = wqb [27648][768]
    GP p1; p1.A = xb; p1.B = wqb; p1.K = HD_; p1.lda = HD_; p1.ldb = HD_;
    p1.sAb = 0; p1.sAn = 0; p1.sBb = 0; p1.sBn = 0;
    p1.o0 = QKn; p1.o2 = Vt; p1.bias = b_qkv;
    gemm_bt<0><<<dim3(D3_/128, rows_c/128, 1), dim3(256), 0, stream>>>(p1);

    // scores: A = Q rows (natural), B = K rows (natural), z = zb*12+zn
    GP p2; p2.A = QKn; p2.B = QKn + NHD_; p2.K = HD_; p2.lda = QKLD_; p2.ldb = QKLD_;
    p2.sAb = (long)S_*QKLD_; p2.sAn = HD_;
    p2.sBb = (long)S_*QKLD_; p2.sBn = HD_;
    p2.o0 = SP; p2.o2 = nullptr; p2.bias = nullptr;
    gemm_bt<1><<<dim3(S_/128, S_/128, zc), dim3(256), 0, stream>>>(p2);

    softmax_rows<<<dim3(zc*S_/4), dim3(256), 0, stream>>>(SP, mask + (long)c*bc*S_);

    // AV: A = P [z][q][k], B = Vt [z][h][s]; H into Q-section (ld 18432)
    GP p3; p3.A = SP; p3.B = Vt; p3.K = S_; p3.lda = S_; p3.ldb = S_;
    p3.sAb = (long)NH_*S_*S_; p3.sAn = (long)S_*S_;
    p3.sBb = (long)NH_*S_*HD_; p3.sBn = (long)S_*HD_;
    p3.o0 = H; p3.o2 = nullptr; p3.bias = nullptr;
    gemm_bt<2><<<dim3(HD_/128, S_/128, zc), dim3(256), 0, stream>>>(p3);

    // out projection: split-K(4) partials into SP (dead), then combine + bias
    GP p4; p4.A = H; p4.B = wob; p4.K = NHD_/4; p4.lda = QKLD_; p4.ldb = NHD_;
    p4.sAb = 0; p4.sAn = NHD_/4;   // z in 0..3 -> zb=0, zn=z -> offset z*2304
    p4.sBb = 0; p4.sBn = NHD_/4;
    p4.o0 = Part; p4.o2 = nullptr; p4.bias = nullptr;
    gemm_bt<3><<<dim3(HD_/128, rows_c/128, 4), dim3(256), 0, stream>>>(p4);

    combine_out<<<dim3(rows_c*HD_/4/256), dim3(256), 0, stream>>>(
        (const float4*)Part, b_o, (float4*)(out + row0*HD_), rows_c*HD_/4);
  }
}

// Round 9
// 611.327 us; speedup vs baseline: 1.0226x; 1.0035x over previous
//
#include <hip/hip_runtime.h>
#include <hip/hip_bf16.h>
#include <stdint.h>

#define AS1 __attribute__((address_space(1)))
#define AS3 __attribute__((address_space(3)))

typedef __attribute__((ext_vector_type(8))) __bf16 bf16x8;
typedef __attribute__((ext_vector_type(4))) float f32x4;
typedef unsigned short u16;
typedef __attribute__((ext_vector_type(8))) unsigned short u16x8;

// ---- problem sizes (fixed for this module) ----
#define B_    8
#define S_    512
#define NH_   12
#define HD_   768
#define NHD_  (NH_*HD_)     // 9216
#define D3_   (3*NHD_)      // 27648
#define QKLD_ (2*NHD_)      // 18432: natural Q|K layout leading dim
#define QK_SCALE 0.03608439182435161f   // 1/sqrt(768)

__device__ __forceinline__ u16 f2bf(float x) {
  union { float f; unsigned u; } a; a.f = x;
  unsigned r = a.u + 0x7fffu + ((a.u >> 16) & 1u);   // RNE
  return (u16)(r >> 16);
}
__device__ __forceinline__ float bf2f(u16 x) {
  union { unsigned u; float f; } a; a.u = ((unsigned)x) << 16; return a.f;
}
// packed RNE f32x2 -> bf16x2 (one VALU inst per pair)
__device__ __forceinline__ uint2 pack4(float a, float b, float c, float d) {
  uint2 r;
  asm("v_cvt_pk_bf16_f32 %0, %1, %2" : "=v"(r.x) : "v"(a), "v"(b));
  asm("v_cvt_pk_bf16_f32 %0, %1, %2" : "=v"(r.y) : "v"(c), "v"(d));
  return r;
}

__device__ __forceinline__ void gload16(const void* g, void* l) {
  // async global->LDS; LDS dest = wave-uniform base + lane*16, global src per-lane
  __builtin_amdgcn_global_load_lds((const AS1 void*)g, (AS3 void*)l, 16, 0, 0);
}

// ============================================================================
// 128x128 GEMM, 256 threads (2x2 waves), BK=64, single-buffer 32KB LDS,
// 4 blocks/CU (VGPR-capped) -> cross-block TLP hides prologue/epilogue.
// T2 XOR swizzle (verified 0 conflicts, rounds 6-8).
// OPERAND-SWAPPED MFMA: mfma(bv, av) -> D quad = 4 consecutive N-cols for a
// fixed M-row (m = lane&15 base, n = (lane>>4)*4 quad) -> vectorized stores.
// Compile-time LDA/LDB/K -> constant-folded staging addresses.
// XCD swizzle (bid&7 = XCD heuristic; perf-only):
//  MODE 0: each XCD owns 27 n-tiles, m fastest (B-panel L2-resident)
//  MODE 1/2: all blocks of a head z on one XCD (panels L2-resident); fallback
//            plain when zc%8 != 0
//  MODE 3: 2 XCDs per K-chunk, n fixed while m walks
// MODE 0: QKV proj -> Q|K natural [row][18432] uint2; V -> Vt (z,h,s) scalar
// MODE 1: scores -> S bf16 [z][row][col] * QK_SCALE (uint2)
// MODE 2: AV     -> H at (zb*512+row)*18432 + zn*768 + col (uint2)
// MODE 3: out-proj split-K partial -> fp32 Part[z][row][col] (float4)
// ============================================================================
struct GP {
  const u16* A;   // + zb*sAb + zn*sAn
  const u16* B;   // + zb*sBb + zn*sBn   (C = A * B^T)
  long sAb, sAn, sBb, sBn;
  void* o0; void* o2;
  const float* bias;
  int mMask, mShift, zPerX;
};

template<int MODE, int LDA, int LDB, int KK>
__global__ __launch_bounds__(256)
void gemm_bt(GP p) {
  __shared__ __align__(16) char smem[32768];   // A tile 16KB | B tile 16KB
  const int tid  = threadIdx.x;
  const int wave = tid >> 6, lane = tid & 63;
  const int wr = wave >> 1, wc = wave & 1;     // 2x2 waves, 64x64 each

  // ---- flattened grid with XCD-locality mapping ----
  const int bid = blockIdx.x;
  const int xcd = bid & 7, loc = bid >> 3;
  int m_idx, n_idx, z;
  if constexpr (MODE == 0) {
    m_idx = loc & p.mMask; n_idx = xcd * 27 + (loc >> p.mShift); z = 0;
  } else if constexpr (MODE == 1) {
    int inner;
    if (p.zPerX) { inner = loc & 15; z = xcd * p.zPerX + (loc >> 4); }
    else         { inner = bid & 15; z = bid >> 4; }
    m_idx = inner >> 2; n_idx = inner & 3;
  } else if constexpr (MODE == 2) {
    int inner;
    if (p.zPerX) { inner = loc % 24; z = xcd * p.zPerX + loc / 24; }
    else         { inner = bid % 24; z = bid / 24; }
    m_idx = inner / 6; n_idx = inner - (inner / 6) * 6;
  } else {
    m_idx = loc & p.mMask;
    n_idx = (xcd & 1) * 3 + (loc >> p.mShift);   // 0..5
    z = xcd >> 1;                                 // K-chunk 0..3
  }
  const int bm0 = m_idx * 128, bn0 = n_idx * 128;
  const int zb  = z / NH_, zn = z - zb * NH_;

  const u16* A  = p.A + zb * p.sAb + zn * p.sAn;
  const u16* Bm = p.B + zb * p.sBb + zn * p.sBn;

  f32x4 acc[4][4];
  const f32x4 zero4 = {0.f, 0.f, 0.f, 0.f};
#pragma unroll
  for (int i = 0; i < 4; ++i)
#pragma unroll
    for (int j = 0; j < 4; ++j) acc[i][j] = zero4;

  // staging with pre-swizzled source column (verified rounds 6-8)
  const int scolsw = ((lane & 7) ^ (lane >> 3)) * 8;   // elements
  const u16* gA = A  + (size_t)(bm0 + wave*8 + (lane>>3)) * LDA + scolsw;
  const u16* gB = Bm + (size_t)(bn0 + wave*8 + (lane>>3)) * LDB + scolsw;
  char* ldsA = smem;
  char* ldsB = smem + 16384;
  char* stA  = ldsA + wave*1024;
  char* stB  = ldsB + wave*1024;

  // fragment read bases (row part) + per-kk swizzled column offsets
  const int aRow = (wr*64 + (lane&15)) * 128;
  const int bRow = (wc*64 + (lane&15)) * 128;
  const int csw  = lane & 7;
  const int cOff0 = (((lane>>4)    ) ^ csw) << 4;   // kk=0
  const int cOff1 = ((4 + (lane>>4)) ^ csw) << 4;   // kk=1

  for (int k0 = 0; k0 < KK; k0 += 64) {
#pragma unroll
    for (int i = 0; i < 4; ++i) {
      gload16(gA + (size_t)i*32*LDA, stA + i*4096);
      gload16(gB + (size_t)i*32*LDB, stB + i*4096);
    }
    gA += 64; gB += 64;
    __syncthreads();
#pragma unroll
    for (int kk = 0; kk < 2; ++kk) {
      const int cOff = kk ? cOff1 : cOff0;
      bf16x8 av[4], bv[4];
#pragma unroll
      for (int i = 0; i < 4; ++i)
        av[i] = *(const bf16x8*)(ldsA + aRow + i*2048 + cOff);
#pragma unroll
      for (int j = 0; j < 4; ++j)
        bv[j] = *(const bf16x8*)(ldsB + bRow + j*2048 + cOff);
      // swapped operands: D quad = consecutive n, lane&15 = m
#pragma unroll
      for (int i = 0; i < 4; ++i)
#pragma unroll
        for (int j = 0; j < 4; ++j)
          acc[i][j] = __builtin_amdgcn_mfma_f32_16x16x32_bf16(bv[j], av[i], acc[i][j], 0, 0, 0);
    }
    __syncthreads();
  }

  // epilogue (swapped layout): m = bm0+wr*64+i*16+(lane&15),
  //                            n = bn0+wc*64+j*16+(lane>>4)*4 + r
  const int mBase = bm0 + wr*64 + (lane & 15);
  const int nBase = bn0 + wc*64 + ((lane >> 4) << 2);
#pragma unroll
  for (int i = 0; i < 4; ++i) {
    const int m = mBase + i*16;
#pragma unroll
    for (int j = 0; j < 4; ++j) {
      const int n = nBase + j*16;
      const f32x4 v = acc[i][j];
      if constexpr (MODE == 0) {
        const float4 b4 = *(const float4*)(p.bias + n);
        if (bn0 < QKLD_) {
          *(uint2*)((u16*)p.o0 + (long)m * QKLD_ + n) =
              pack4(v[0]+b4.x, v[1]+b4.y, v[2]+b4.z, v[3]+b4.w);
        } else {
          const int vcol = n - QKLD_;
          const int nh = vcol / HD_;
          const int h  = vcol - nh * HD_;
          u16* vb = (u16*)p.o2 + (long)((m >> 9) * NH_ + nh) * (S_*HD_)
                    + (long)h * S_ + (m & 511);
          vb[0]    = f2bf(v[0]+b4.x);
          vb[512]  = f2bf(v[1]+b4.y);
          vb[1024] = f2bf(v[2]+b4.z);
          vb[1536] = f2bf(v[3]+b4.w);
        }
      } else if constexpr (MODE == 1) {
        *(uint2*)((u16*)p.o0 + (long)z*S_*S_ + (long)m*S_ + n) =
            pack4(v[0]*QK_SCALE, v[1]*QK_SCALE, v[2]*QK_SCALE, v[3]*QK_SCALE);
      } else if constexpr (MODE == 2) {
        *(uint2*)((u16*)p.o0 + (long)(zb*S_ + m)*QKLD_ + zn*HD_ + n) =
            pack4(v[0], v[1], v[2], v[3]);
      } else {
        const long rowsTot = (long)(p.mMask + 1) * 128;
        *(float4*)((float*)p.o0 + ((long)z * rowsTot + m) * HD_ + n) =
            *(const float4*)&v;
      }
    }
  }
}

// one wave per row (512 cols, bf16, IN-PLACE): +mask, softmax
__global__ __launch_bounds__(256)
void softmax_rows(u16* __restrict__ SP, const float* __restrict__ maskc) {
  const int wave = threadIdx.x >> 6, lane = threadIdx.x & 63;
  const int rid = blockIdx.x * 4 + wave;
  const int z = rid >> 9;
  const int b = z / NH_;
  const u16x8 sv = *(const u16x8*)(SP + (size_t)rid * S_ + lane*8);
  const float* mrow = maskc + (size_t)b * S_;
  float vals[8];
  float m = -3.4e38f;
#pragma unroll
  for (int j = 0; j < 8; ++j) {
    vals[j] = bf2f(sv[j]) + mrow[lane*8 + j];
    m = fmaxf(m, vals[j]);
  }
#pragma unroll
  for (int o = 32; o > 0; o >>= 1) m = fmaxf(m, __shfl_xor(m, o));
  float sum = 0.f;
#pragma unroll
  for (int j = 0; j < 8; ++j) { vals[j] = __expf(vals[j] - m); sum += vals[j]; }
#pragma unroll
  for (int o = 32; o > 0; o >>= 1) sum += __shfl_xor(sum, o);
  const float inv = 1.0f / sum;
  u16x8 pv;
#pragma unroll
  for (int j = 0; j < 8; ++j) pv[j] = f2bf(vals[j] * inv);
  *(u16x8*)(SP + (size_t)rid * S_ + lane*8) = pv;
}

__global__ __launch_bounds__(256)
void cvt_bf16(const float4* __restrict__ in, ushort4* __restrict__ out, int n4) {
  const int i = blockIdx.x * 256 + threadIdx.x;
  if (i >= n4) return;
  const float4 v = in[i];
  ushort4 o;
  o.x = f2bf(v.x); o.y = f2bf(v.y); o.z = f2bf(v.z); o.w = f2bf(v.w);
  out[i] = o;
}

// out = sum of 4 fp32 partials + bias; n4 = rows_c*768/4 (float4 units)
__global__ __launch_bounds__(256)
void combine_out(const float4* __restrict__ part, const float* __restrict__ b,
                 float4* __restrict__ out, int n4) {
  const int i = blockIdx.x * 256 + threadIdx.x;
  if (i >= n4) return;
  const float4 a0 = part[i];
  const float4 a1 = part[i + (size_t)n4];
  const float4 a2 = part[i + (size_t)2*n4];
  const float4 a3 = part[i + (size_t)3*n4];
  const int c = (i * 4) % HD_;
  float4 o;
  o.x = a0.x + a1.x + a2.x + a3.x + b[c];
  o.y = a0.y + a1.y + a2.y + a3.y + b[c+1];
  o.z = a0.z + a1.z + a2.z + a3.z + b[c+2];
  o.w = a0.w + a1.w + a2.w + a3.w + b[c+3];
  out[i] = o;
}

extern "C" void kernel_launch(void* const* d_in, const int* in_sizes, int n_in,
                              void* d_out, int out_size, void* d_ws, size_t ws_size,
                              hipStream_t stream) {
  const float* x     = (const float*)d_in[0];
  const float* mask  = (const float*)d_in[1];
  const float* w_qkv = (const float*)d_in[2];
  const float* b_qkv = (const float*)d_in[3];
  const float* w_o   = (const float*)d_in[4];
  const float* b_o   = (const float*)d_in[5];
  float* out = (float*)d_out;

  // workspace (same footprint as rounds 2-8):
  // fixed: wqb 42,467,328 | wob 14,155,776  (= 56,623,104)
  // per-bc: xb 786,432 | QKn 18,874,368 | Vt 9,437,184 | SP 6,291,456
  // aliases: P = SP in-place; H = QKn Q-section (ld 18432); Part = SP
  int bc = 0;
  for (int c = 8; c >= 1; c >>= 1)
    if (56623104UL + (unsigned long)c*35389440UL <= ws_size) { bc = c; break; }
  if (bc == 0) return;

  char* ws = (char*)d_ws;
  u16* wqb = (u16*)(ws);
  u16* wob = (u16*)(ws + 42467328L);
  u16* xb  = (u16*)(ws + 56623104L);
  long off = 56623104L + (long)bc*786432L;
  u16* QKn = (u16*)(ws + off);  off += (long)bc*18874368L;
  u16* Vt  = (u16*)(ws + off);  off += (long)bc*9437184L;
  u16* SP  = (u16*)(ws + off);
  u16* H   = QKn;                // alias: Q-section, ld 18432
  float* Part = (float*)SP;      // alias: 4 x rows_c x 768 fp32 = SP bytes

  cvt_bf16<<<dim3(D3_*HD_/4/256), dim3(256), 0, stream>>>((const float4*)w_qkv, (ushort4*)wqb, D3_*HD_/4);
  cvt_bf16<<<dim3(HD_*NHD_/4/256), dim3(256), 0, stream>>>((const float4*)w_o, (ushort4*)wob, HD_*NHD_/4);

  const int nchunks = B_ / bc;
  const int rows_c = bc * S_;
  const int zc = bc * NH_;
  const int mT = rows_c / 128;               // {4,8,16,32}
  const int mShift = __builtin_ctz(mT);
  const int zPerX = (zc % 8 == 0) ? zc / 8 : 0;

  for (int c = 0; c < nchunks; ++c) {
    const long row0 = (long)c * rows_c;

    cvt_bf16<<<dim3(rows_c*HD_/4/256), dim3(256), 0, stream>>>(
        (const float4*)(x + row0*HD_), (ushort4*)xb, rows_c*HD_/4);

    // QKV: A = xb [rows_c][768], B = wqb [27648][768]
    GP p1; p1.A = xb; p1.B = wqb;
    p1.sAb = 0; p1.sAn = 0; p1.sBb = 0; p1.sBn = 0;
    p1.o0 = QKn; p1.o2 = Vt; p1.bias = b_qkv;
    p1.mMask = mT - 1; p1.mShift = mShift; p1.zPerX = 0;
    gemm_bt<0, HD_, HD_, HD_><<<dim3(216 * mT), dim3(256), 0, stream>>>(p1);

    // scores: A = Q rows (natural), B = K rows (natural)
    GP p2; p2.A = QKn; p2.B = QKn + NHD_;
    p2.sAb = (long)S_*QKLD_; p2.sAn = HD_;
    p2.sBb = (long)S_*QKLD_; p2.sBn = HD_;
    p2.o0 = SP; p2.o2 = nullptr; p2.bias = nullptr;
    p2.mMask = 0; p2.mShift = 0; p2.zPerX = zPerX;
    gemm_bt<1, QKLD_, QKLD_, HD_><<<dim3(zc * 16), dim3(256), 0, stream>>>(p2);

    softmax_rows<<<dim3(zc*S_/4), dim3(256), 0, stream>>>(SP, mask + (long)c*bc*S_);

    // AV: A = P [z][q][k], B = Vt [z][h][s]; H into Q-section (ld 18432)
    GP p3; p3.A = SP; p3.B = Vt;
    p3.sAb = (long)NH_*S_*S_; p3.sAn = (long)S_*S_;
    p3.sBb = (long)NH_*S_*HD_; p3.sBn = (long)S_*HD_;
    p3.o0 = H; p3.o2 = nullptr; p3.bias = nullptr;
    p3.mMask = 0; p3.mShift = 0; p3.zPerX = zPerX;
    gemm_bt<2, S_, S_, S_><<<dim3(zc * 24), dim3(256), 0, stream>>>(p3);

    // out projection: split-K(4) partials into SP (dead), then combine + bias
    GP p4; p4.A = H; p4.B = wob;
    p4.sAb = 0; p4.sAn = NHD_/4;   // z in 0..3 -> zb=0, zn=z -> offset z*2304
    p4.sBb = 0; p4.sBn = NHD_/4;
    p4.o0 = Part; p4.o2 = nullptr; p4.bias = nullptr;
    p4.mMask = mT - 1; p4.mShift = mShift; p4.zPerX = 0;
    gemm_bt<3, QKLD_, NHD_, NHD_/4><<<dim3(24 * mT), dim3(256), 0, stream>>>(p4);

    combine_out<<<dim3(rows_c*HD_/4/256), dim3(256), 0, stream>>>(
        (const float4*)Part, b_o, (float4*)(out + row0*HD_), rows_c*HD_/4);
  }
}

// Round 10
// 525.971 us; speedup vs baseline: 1.1885x; 1.1623x over previous
//
#include <hip/hip_runtime.h>
#include <hip/hip_bf16.h>
#include <stdint.h>

#define AS1 __attribute__((address_space(1)))
#define AS3 __attribute__((address_space(3)))

typedef __attribute__((ext_vector_type(8))) __bf16 bf16x8;
typedef __attribute__((ext_vector_type(4))) float f32x4;
typedef unsigned short u16;
typedef __attribute__((ext_vector_type(8))) unsigned short u16x8;

// ---- problem sizes (fixed for this module) ----
#define B_    8
#define S_    512
#define NH_   12
#define HD_   768
#define NHD_  (NH_*HD_)     // 9216
#define D3_   (3*NHD_)      // 27648
#define QKLD_ (2*NHD_)      // 18432: natural Q|K layout leading dim
#define QK_SCALE 0.03608439182435161f   // 1/sqrt(768)

__device__ __forceinline__ u16 f2bf(float x) {
  union { float f; unsigned u; } a; a.f = x;
  unsigned r = a.u + 0x7fffu + ((a.u >> 16) & 1u);   // RNE
  return (u16)(r >> 16);
}
__device__ __forceinline__ float bf2f(u16 x) {
  union { unsigned u; float f; } a; a.u = ((unsigned)x) << 16; return a.f;
}
// packed RNE f32x2 -> bf16x2 (one VALU inst per pair)
__device__ __forceinline__ uint2 pack4(float a, float b, float c, float d) {
  uint2 r;
  asm("v_cvt_pk_bf16_f32 %0, %1, %2" : "=v"(r.x) : "v"(a), "v"(b));
  asm("v_cvt_pk_bf16_f32 %0, %1, %2" : "=v"(r.y) : "v"(c), "v"(d));
  return r;
}

__device__ __forceinline__ void gload16(const void* g, void* l) {
  // async global->LDS; LDS dest = wave-uniform base + lane*16, global src per-lane
  __builtin_amdgcn_global_load_lds((const AS1 void*)g, (AS3 void*)l, 16, 0, 0);
}

// ============================================================================
// 128x128 GEMM, 256 threads (2x2 waves), BK=64, single-buffer 32KB LDS,
// ~5 blocks/CU -> cross-block TLP hides prologue/epilogue (short-K regime).
// T2 XOR swizzle (verified 0 conflicts, rounds 6-9).
// OPERAND-SWAPPED MFMA (round 9, kept): mfma(bv, av) -> D quad = 4 consecutive
// N-cols for fixed M-row (m = lane&15 base, n = (lane>>4)*4 quad).
// Compile-time LDA/LDB/K (round 9, kept).
// Grid mappings:
//  MODE 0: 2-D grid, n fastest (blockIdx.x) -- REVERTED to round-8 order.
//    Round 9's m-fastest XCD remap thrashed A (6MB) in the 4MB per-XCD L2:
//    cold ~900cy HBM misses per K-step stalled the 1-deep pipeline
//    (MfmaUtil/VALUBusy/BW all fell while time rose). n-fastest keeps one
//    196KB A-panel L2-hot for 216 consecutive blocks.
//  MODE 1/2: all blocks of a head z on one XCD (kept; improved round 9)
//  MODE 3: 2 XCDs per K-chunk (kept)
// MODE 0: QKV proj -> Q|K natural [row][18432] uint2; V -> Vt (z,h,s)
// MODE 1: scores -> S bf16 [z][row][col] * QK_SCALE (uint2)
// MODE 2: AV     -> H at (zb*512+row)*18432 + zn*768 + col (uint2)
// MODE 3: out-proj split-K partial -> fp32 Part[z][row][col] (float4)
// ============================================================================
struct GP {
  const u16* A;   // + zb*sAb + zn*sAn
  const u16* B;   // + zb*sBb + zn*sBn   (C = A * B^T)
  long sAb, sAn, sBb, sBn;
  void* o0; void* o2;
  const float* bias;
  int mMask, mShift, zPerX;
};

template<int MODE, int LDA, int LDB, int KK>
__global__ __launch_bounds__(256)
void gemm_bt(GP p) {
  __shared__ __align__(16) char smem[32768];   // A tile 16KB | B tile 16KB
  const int tid  = threadIdx.x;
  const int wave = tid >> 6, lane = tid & 63;
  const int wr = wave >> 1, wc = wave & 1;     // 2x2 waves, 64x64 each

  // ---- grid mapping ----
  int m_idx, n_idx, z;
  if constexpr (MODE == 0) {
    m_idx = blockIdx.y; n_idx = blockIdx.x; z = 0;   // n fastest (round-8 order)
  } else {
    const int bid = blockIdx.x;
    const int xcd = bid & 7, loc = bid >> 3;
    if constexpr (MODE == 1) {
      int inner;
      if (p.zPerX) { inner = loc & 15; z = xcd * p.zPerX + (loc >> 4); }
      else         { inner = bid & 15; z = bid >> 4; }
      m_idx = inner >> 2; n_idx = inner & 3;
    } else if constexpr (MODE == 2) {
      int inner;
      if (p.zPerX) { inner = loc % 24; z = xcd * p.zPerX + loc / 24; }
      else         { inner = bid % 24; z = bid / 24; }
      m_idx = inner / 6; n_idx = inner - (inner / 6) * 6;
    } else {
      m_idx = loc & p.mMask;
      n_idx = (xcd & 1) * 3 + (loc >> p.mShift);   // 0..5
      z = xcd >> 1;                                 // K-chunk 0..3
    }
  }
  const int bm0 = m_idx * 128, bn0 = n_idx * 128;
  const int zb  = z / NH_, zn = z - zb * NH_;

  const u16* A  = p.A + zb * p.sAb + zn * p.sAn;
  const u16* Bm = p.B + zb * p.sBb + zn * p.sBn;

  f32x4 acc[4][4];
  const f32x4 zero4 = {0.f, 0.f, 0.f, 0.f};
#pragma unroll
  for (int i = 0; i < 4; ++i)
#pragma unroll
    for (int j = 0; j < 4; ++j) acc[i][j] = zero4;

  // staging with pre-swizzled source column (verified rounds 6-9)
  const int scolsw = ((lane & 7) ^ (lane >> 3)) * 8;   // elements
  const u16* gA = A  + (size_t)(bm0 + wave*8 + (lane>>3)) * LDA + scolsw;
  const u16* gB = Bm + (size_t)(bn0 + wave*8 + (lane>>3)) * LDB + scolsw;
  char* ldsA = smem;
  char* ldsB = smem + 16384;
  char* stA  = ldsA + wave*1024;
  char* stB  = ldsB + wave*1024;

  // fragment read bases (row part) + per-kk swizzled column offsets
  const int aRow = (wr*64 + (lane&15)) * 128;
  const int bRow = (wc*64 + (lane&15)) * 128;
  const int csw  = lane & 7;
  const int cOff0 = (((lane>>4)    ) ^ csw) << 4;   // kk=0
  const int cOff1 = ((4 + (lane>>4)) ^ csw) << 4;   // kk=1

  for (int k0 = 0; k0 < KK; k0 += 64) {
#pragma unroll
    for (int i = 0; i < 4; ++i) {
      gload16(gA + (size_t)i*32*LDA, stA + i*4096);
      gload16(gB + (size_t)i*32*LDB, stB + i*4096);
    }
    gA += 64; gB += 64;
    __syncthreads();
#pragma unroll
    for (int kk = 0; kk < 2; ++kk) {
      const int cOff = kk ? cOff1 : cOff0;
      bf16x8 av[4], bv[4];
#pragma unroll
      for (int i = 0; i < 4; ++i)
        av[i] = *(const bf16x8*)(ldsA + aRow + i*2048 + cOff);
#pragma unroll
      for (int j = 0; j < 4; ++j)
        bv[j] = *(const bf16x8*)(ldsB + bRow + j*2048 + cOff);
      // swapped operands: D quad = consecutive n, lane&15 = m
#pragma unroll
      for (int i = 0; i < 4; ++i)
#pragma unroll
        for (int j = 0; j < 4; ++j)
          acc[i][j] = __builtin_amdgcn_mfma_f32_16x16x32_bf16(bv[j], av[i], acc[i][j], 0, 0, 0);
    }
    __syncthreads();
  }

  // epilogue (swapped layout): m = bm0+wr*64+i*16+(lane&15),
  //                            n = bn0+wc*64+j*16+(lane>>4)*4 + r
  const int mBase = bm0 + wr*64 + (lane & 15);
  const int nBase = bn0 + wc*64 + ((lane >> 4) << 2);
#pragma unroll
  for (int i = 0; i < 4; ++i) {
    const int m = mBase + i*16;
#pragma unroll
    for (int j = 0; j < 4; ++j) {
      const int n = nBase + j*16;
      const f32x4 v = acc[i][j];
      if constexpr (MODE == 0) {
        const float4 b4 = *(const float4*)(p.bias + n);
        if (bn0 < QKLD_) {
          *(uint2*)((u16*)p.o0 + (long)m * QKLD_ + n) =
              pack4(v[0]+b4.x, v[1]+b4.y, v[2]+b4.z, v[3]+b4.w);
        } else {
          const int vcol = n - QKLD_;
          const int nh = vcol / HD_;
          const int h  = vcol - nh * HD_;
          u16* vb = (u16*)p.o2 + (long)((m >> 9) * NH_ + nh) * (S_*HD_)
                    + (long)h * S_ + (m & 511);
          vb[0]    = f2bf(v[0]+b4.x);
          vb[512]  = f2bf(v[1]+b4.y);
          vb[1024] = f2bf(v[2]+b4.z);
          vb[1536] = f2bf(v[3]+b4.w);
        }
      } else if constexpr (MODE == 1) {
        *(uint2*)((u16*)p.o0 + (long)z*S_*S_ + (long)m*S_ + n) =
            pack4(v[0]*QK_SCALE, v[1]*QK_SCALE, v[2]*QK_SCALE, v[3]*QK_SCALE);
      } else if constexpr (MODE == 2) {
        *(uint2*)((u16*)p.o0 + (long)(zb*S_ + m)*QKLD_ + zn*HD_ + n) =
            pack4(v[0], v[1], v[2], v[3]);
      } else {
        const long rowsTot = (long)(p.mMask + 1) * 128;
        *(float4*)((float*)p.o0 + ((long)z * rowsTot + m) * HD_ + n) =
            *(const float4*)&v;
      }
    }
  }
}

// one wave per row (512 cols, bf16, IN-PLACE): +mask, softmax
__global__ __launch_bounds__(256)
void softmax_rows(u16* __restrict__ SP, const float* __restrict__ maskc) {
  const int wave = threadIdx.x >> 6, lane = threadIdx.x & 63;
  const int rid = blockIdx.x * 4 + wave;
  const int z = rid >> 9;
  const int b = z / NH_;
  const u16x8 sv = *(const u16x8*)(SP + (size_t)rid * S_ + lane*8);
  const float* mrow = maskc + (size_t)b * S_;
  float vals[8];
  float m = -3.4e38f;
#pragma unroll
  for (int j = 0; j < 8; ++j) {
    vals[j] = bf2f(sv[j]) + mrow[lane*8 + j];
    m = fmaxf(m, vals[j]);
  }
#pragma unroll
  for (int o = 32; o > 0; o >>= 1) m = fmaxf(m, __shfl_xor(m, o));
  float sum = 0.f;
#pragma unroll
  for (int j = 0; j < 8; ++j) { vals[j] = __expf(vals[j] - m); sum += vals[j]; }
#pragma unroll
  for (int o = 32; o > 0; o >>= 1) sum += __shfl_xor(sum, o);
  const float inv = 1.0f / sum;
  u16x8 pv;
#pragma unroll
  for (int j = 0; j < 8; ++j) pv[j] = f2bf(vals[j] * inv);
  *(u16x8*)(SP + (size_t)rid * S_ + lane*8) = pv;
}

__global__ __launch_bounds__(256)
void cvt_bf16(const float4* __restrict__ in, ushort4* __restrict__ out, int n4) {
  const int i = blockIdx.x * 256 + threadIdx.x;
  if (i >= n4) return;
  const float4 v = in[i];
  ushort4 o;
  o.x = f2bf(v.x); o.y = f2bf(v.y); o.z = f2bf(v.z); o.w = f2bf(v.w);
  out[i] = o;
}

// out = sum of 4 fp32 partials + bias; n4 = rows_c*768/4 (float4 units)
__global__ __launch_bounds__(256)
void combine_out(const float4* __restrict__ part, const float* __restrict__ b,
                 float4* __restrict__ out, int n4) {
  const int i = blockIdx.x * 256 + threadIdx.x;
  if (i >= n4) return;
  const float4 a0 = part[i];
  const float4 a1 = part[i + (size_t)n4];
  const float4 a2 = part[i + (size_t)2*n4];
  const float4 a3 = part[i + (size_t)3*n4];
  const int c = (i * 4) % HD_;
  float4 o;
  o.x = a0.x + a1.x + a2.x + a3.x + b[c];
  o.y = a0.y + a1.y + a2.y + a3.y + b[c+1];
  o.z = a0.z + a1.z + a2.z + a3.z + b[c+2];
  o.w = a0.w + a1.w + a2.w + a3.w + b[c+3];
  out[i] = o;
}

extern "C" void kernel_launch(void* const* d_in, const int* in_sizes, int n_in,
                              void* d_out, int out_size, void* d_ws, size_t ws_size,
                              hipStream_t stream) {
  const float* x     = (const float*)d_in[0];
  const float* mask  = (const float*)d_in[1];
  const float* w_qkv = (const float*)d_in[2];
  const float* b_qkv = (const float*)d_in[3];
  const float* w_o   = (const float*)d_in[4];
  const float* b_o   = (const float*)d_in[5];
  float* out = (float*)d_out;

  // workspace (same footprint as rounds 2-9):
  // fixed: wqb 42,467,328 | wob 14,155,776  (= 56,623,104)
  // per-bc: xb 786,432 | QKn 18,874,368 | Vt 9,437,184 | SP 6,291,456
  // aliases: P = SP in-place; H = QKn Q-section (ld 18432); Part = SP
  int bc = 0;
  for (int c = 8; c >= 1; c >>= 1)
    if (56623104UL + (unsigned long)c*35389440UL <= ws_size) { bc = c; break; }
  if (bc == 0) return;

  char* ws = (char*)d_ws;
  u16* wqb = (u16*)(ws);
  u16* wob = (u16*)(ws + 42467328L);
  u16* xb  = (u16*)(ws + 56623104L);
  long off = 56623104L + (long)bc*786432L;
  u16* QKn = (u16*)(ws + off);  off += (long)bc*18874368L;
  u16* Vt  = (u16*)(ws + off);  off += (long)bc*9437184L;
  u16* SP  = (u16*)(ws + off);
  u16* H   = QKn;                // alias: Q-section, ld 18432
  float* Part = (float*)SP;      // alias: 4 x rows_c x 768 fp32 = SP bytes

  cvt_bf16<<<dim3(D3_*HD_/4/256), dim3(256), 0, stream>>>((const float4*)w_qkv, (ushort4*)wqb, D3_*HD_/4);
  cvt_bf16<<<dim3(HD_*NHD_/4/256), dim3(256), 0, stream>>>((const float4*)w_o, (ushort4*)wob, HD_*NHD_/4);

  const int nchunks = B_ / bc;
  const int rows_c = bc * S_;
  const int zc = bc * NH_;
  const int mT = rows_c / 128;               // {4,8,16,32}
  const int mShift = __builtin_ctz(mT);
  const int zPerX = (zc % 8 == 0) ? zc / 8 : 0;

  for (int c = 0; c < nchunks; ++c) {
    const long row0 = (long)c * rows_c;

    cvt_bf16<<<dim3(rows_c*HD_/4/256), dim3(256), 0, stream>>>(
        (const float4*)(x + row0*HD_), (ushort4*)xb, rows_c*HD_/4);

    // QKV: A = xb [rows_c][768], B = wqb [27648][768]; 2-D grid, n fastest
    GP p1; p1.A = xb; p1.B = wqb;
    p1.sAb = 0; p1.sAn = 0; p1.sBb = 0; p1.sBn = 0;
    p1.o0 = QKn; p1.o2 = Vt; p1.bias = b_qkv;
    p1.mMask = mT - 1; p1.mShift = mShift; p1.zPerX = 0;
    gemm_bt<0, HD_, HD_, HD_><<<dim3(216, mT, 1), dim3(256), 0, stream>>>(p1);

    // scores: A = Q rows (natural), B = K rows (natural)
    GP p2; p2.A = QKn; p2.B = QKn + NHD_;
    p2.sAb = (long)S_*QKLD_; p2.sAn = HD_;
    p2.sBb = (long)S_*QKLD_; p2.sBn = HD_;
    p2.o0 = SP; p2.o2 = nullptr; p2.bias = nullptr;
    p2.mMask = 0; p2.mShift = 0; p2.zPerX = zPerX;
    gemm_bt<1, QKLD_, QKLD_, HD_><<<dim3(zc * 16), dim3(256), 0, stream>>>(p2);

    softmax_rows<<<dim3(zc*S_/4), dim3(256), 0, stream>>>(SP, mask + (long)c*bc*S_);

    // AV: A = P [z][q][k], B = Vt [z][h][s]; H into Q-section (ld 18432)
    GP p3; p3.A = SP; p3.B = Vt;
    p3.sAb = (long)NH_*S_*S_; p3.sAn = (long)S_*S_;
    p3.sBb = (long)NH_*S_*HD_; p3.sBn = (long)S_*HD_;
    p3.o0 = H; p3.o2 = nullptr; p3.bias = nullptr;
    p3.mMask = 0; p3.mShift = 0; p3.zPerX = zPerX;
    gemm_bt<2, S_, S_, S_><<<dim3(zc * 24), dim3(256), 0, stream>>>(p3);

    // out projection: split-K(4) partials into SP (dead), then combine + bias
    GP p4; p4.A = H; p4.B = wob;
    p4.sAb = 0; p4.sAn = NHD_/4;   // z in 0..3 -> zb=0, zn=z -> offset z*2304
    p4.sBb = 0; p4.sBn = NHD_/4;
    p4.o0 = Part; p4.o2 = nullptr; p4.bias = nullptr;
    p4.mMask = mT - 1; p4.mShift = mShift; p4.zPerX = 0;
    gemm_bt<3, QKLD_, NHD_, NHD_/4><<<dim3(24 * mT), dim3(256), 0, stream>>>(p4);

    combine_out<<<dim3(rows_c*HD_/4/256), dim3(256), 0, stream>>>(
        (const float4*)Part, b_o, (float4*)(out + row0*HD_), rows_c*HD_/4);
  }
}